// Round 22
// baseline (353.488 us; speedup 1.0000x reference)
//
#include <hip/hip_runtime.h>

typedef unsigned short u16;
typedef _Float16 f16x8 __attribute__((ext_vector_type(8)));
typedef float f32x4 __attribute__((ext_vector_type(4)));
typedef u16 u16x4 __attribute__((ext_vector_type(4)));
typedef u16 u16x8v __attribute__((ext_vector_type(8)));

__device__ __forceinline__ u16 f2h(float f) {
    _Float16 h = (_Float16)f;
    return __builtin_bit_cast(u16, h);
}
__device__ __forceinline__ float h2f(u16 u) {
    return (float)__builtin_bit_cast(_Float16, u);
}

// XCD-aware bijective block remap (T1). Requires total blocks % 8 == 0.
__device__ __forceinline__ unsigned xcd_swz_flat()
{
    unsigned total = gridDim.x * gridDim.y * gridDim.z;
    unsigned flat = (blockIdx.z * gridDim.y + blockIdx.y) * gridDim.x + blockIdx.x;
    return (flat & 7) * (total >> 3) + (flat >> 3);
}

// ----------------------------------------- pack (raw, transposed) + stats ----
__global__ void __launch_bounds__(256) packstat(
    const float* __restrict__ c, const float* __restrict__ s,
    u16* __restrict__ cT, u16* __restrict__ sT,
    float* __restrict__ pS, float* __restrict__ pQ)
{
    __shared__ float tile[32][33];
    int z = blockIdx.z;
    bool isS = z >= 4;
    int b = z & 3;
    const float* src = isS ? s : c;
    u16* dst = isS ? sT : cT;
    int n0 = blockIdx.x * 32, c0 = blockIdx.y * 32;
    int tx = threadIdx.x, ty = threadIdx.y;
    const float* sbp = src + ((size_t)b * 512 + c0) * 4096 + n0;
#pragma unroll
    for (int it = 0; it < 4; ++it) {
        int cc = ty + it * 8;
        tile[cc][tx] = sbp[(size_t)cc * 4096 + tx];
    }
    __syncthreads();
    size_t obase = ((size_t)b * 4096 + n0) * 512 + c0;
#pragma unroll
    for (int it = 0; it < 4; ++it) {
        int r = ty + it * 8;
        dst[obase + (size_t)r * 512 + tx] = f2h(tile[tx][r]);
    }
    if (ty == 0) {
        float sm = 0.f, sq = 0.f;
#pragma unroll
        for (int n = 0; n < 32; ++n) {
            float v = tile[tx][n];
            sm += v; sq += v * v;
        }
        size_t idx = ((size_t)z * 512 + c0 + tx) * 128 + blockIdx.x;
        pS[idx] = sm; pQ[idx] = sq;
    }
}

// -------------------------------------------------------- stats reduce ----
__global__ void __launch_bounds__(64) statreduce(
    const float* __restrict__ pS, const float* __restrict__ pQ,
    float* __restrict__ mC, float* __restrict__ rC,
    float* __restrict__ mS, float* __restrict__ rS)
{
    int row = blockIdx.x;            // z*512 + ch
    int lane = threadIdx.x;
    const float* ps = pS + (size_t)row * 128;
    const float* pq = pQ + (size_t)row * 128;
    float sm = ps[lane] + ps[lane + 64];
    float sq = pq[lane] + pq[lane + 64];
#pragma unroll
    for (int m = 1; m < 64; m <<= 1) {
        sm += __shfl_xor(sm, m);
        sq += __shfl_xor(sq, m);
    }
    if (lane == 0) {
        float mean = sm * (1.0f / 4096.0f);
        float var = (sq - 4096.0f * mean * mean) * (1.0f / 4095.0f);
        float rstd = rsqrtf(var + 1e-5f);
        int z = row >> 9, ch = row & 511;
        int b = z & 3;
        if (z < 4) { mC[b * 512 + ch] = mean; rC[b * 512 + ch] = rstd; }
        else       { mS[b * 512 + ch] = mean; rS[b * 512 + ch] = rstd; }
    }
}

// ------------------------------------------------- fused weight prep ------
__global__ void __launch_bounds__(256) prep_kernel(
    const float* __restrict__ c_w, const float* __restrict__ s_w,
    const float* __restrict__ i_w, const float* __restrict__ o_w,
    u16* __restrict__ cwT, u16* __restrict__ swT,
    u16* __restrict__ iwT, u16* __restrict__ ow)
{
    int z = blockIdx.z;
    int tx = threadIdx.x, ty = threadIdx.y;
    if (z == 3) {
        size_t base = ((size_t)(blockIdx.y * 16 + blockIdx.x) * 256 +
                       (ty * 32 + tx)) * 4;
        float4 v = *(const float4*)(o_w + base);
        u16x4 o;
        o[0] = f2h(v.x); o[1] = f2h(v.y); o[2] = f2h(v.z); o[3] = f2h(v.w);
        *(u16x4*)(ow + base) = o;
        return;
    }
    const float* w = (z == 0) ? c_w : (z == 1) ? s_w : i_w;
    u16* wT = (z == 0) ? cwT : (z == 1) ? swT : iwT;
    __shared__ float tile[32][33];
    int c0 = blockIdx.x * 32, k0 = blockIdx.y * 32;
#pragma unroll
    for (int it = 0; it < 4; ++it) {
        int kk = ty + it * 8;
        tile[kk][tx] = w[(size_t)(k0 + kk) * 512 + c0 + tx];
    }
    __syncthreads();
#pragma unroll
    for (int it = 0; it < 4; ++it) {
        int r = ty + it * 8;
        wT[(size_t)(c0 + r) * 512 + k0 + tx] = f2h(tile[tx][r]);
    }
}

// ------------------------------------------------- fused bias prep --------
__global__ void __launch_bounds__(256) bias_prep(
    const float* __restrict__ o_w, const float* __restrict__ i_b,
    const float* __restrict__ o_b, const float* __restrict__ s_w,
    const float* __restrict__ c_b, float* __restrict__ v,
    float* __restrict__ wu)
{
    __shared__ float buf[512];
    int t = threadIdx.x;
    bool isWu = blockIdx.x >= 2;
    const float* vec = isWu ? c_b : i_b;
    buf[t] = vec[t]; buf[t + 256] = vec[t + 256];
    __syncthreads();
    int o = (blockIdx.x & 1) * 256 + t;
    if (!isWu) {
        float acc = o_b[o];
        const float* row = o_w + (size_t)o * 512;
        for (int k = 0; k < 512; ++k) acc += row[k] * buf[k];
        v[o] = acc;
    } else {
        float acc = 0.f;
        for (int k = 0; k < 512; ++k) acc += buf[k] * s_w[(size_t)k * 512 + o];
        wu[o] = acc;
    }
}

// -------- wb[b,l] = (wu[l] - sum_a mC·rC·G[a,l]) · rS[b,l]  (wave/output) --
__global__ void __launch_bounds__(256) wb_kernel(
    const u16* __restrict__ G, const float* __restrict__ wu,
    const float* __restrict__ mC, const float* __restrict__ rC,
    const float* __restrict__ rS, float* __restrict__ wb)
{
    int t = threadIdx.x, lane = t & 63, wv = t >> 6;
    int gid = blockIdx.x * 4 + wv;       // over B*512
    int b = gid >> 9, l = gid & 511;
    float acc = 0.f;
#pragma unroll
    for (int i = 0; i < 8; ++i) {
        int a = lane * 8 + i;
        acc += mC[b * 512 + a] * rC[b * 512 + a] * h2f(G[(size_t)a * 512 + l]);
    }
#pragma unroll
    for (int m = 1; m < 64; m <<= 1) acc += __shfl_xor(acc, m);
    if (!lane) wb[b * 512 + l] = (wu[l] - acc) * rS[b * 512 + l];
}

// ---------------------- Gb[b][a][l] = rC[b,a] · G[a,l] · rS[b,l]  (f16) ----
__global__ void __launch_bounds__(256) gbscale(
    const u16* __restrict__ G, const float* __restrict__ rC,
    const float* __restrict__ rS, u16* __restrict__ Gb)
{
    int b = blockIdx.y;
    size_t idx = ((size_t)blockIdx.x * 256 + threadIdx.x) * 8; // over 512*512
    int a = (int)(idx >> 9), l0 = (int)(idx & 511);
    float ra = rC[b * 512 + a];
    u16x8v g = *(const u16x8v*)(G + idx);
    const float4* q4 = (const float4*)(rS + b * 512 + l0);
    float4 q0 = q4[0], q1 = q4[1];
    u16x8v o;
    o[0] = f2h(ra * h2f(g[0]) * q0.x); o[1] = f2h(ra * h2f(g[1]) * q0.y);
    o[2] = f2h(ra * h2f(g[2]) * q0.z); o[3] = f2h(ra * h2f(g[3]) * q0.w);
    o[4] = f2h(ra * h2f(g[4]) * q1.x); o[5] = f2h(ra * h2f(g[5]) * q1.y);
    o[6] = f2h(ra * h2f(g[6]) * q1.z); o[7] = f2h(ra * h2f(g[7]) * q1.w);
    *(u16x8v*)(Gb + (size_t)b * 262144 + idx) = o;
}

// u[b,r] = sum_l sT[b,r,l] * wb[b,l]
__global__ void __launch_bounds__(256) rowdot_kernel(
    const u16* __restrict__ sT, const float* __restrict__ wb,
    float* __restrict__ u)
{
    __shared__ float swu[512];
    int t = threadIdx.x;
    const float* wbb = wb + (size_t)(blockIdx.x >> 10) * 512;
    swu[t] = wbb[t]; swu[t + 256] = wbb[t + 256];
    __syncthreads();
    int lane = t & 63, wv = t >> 6;
    int row = blockIdx.x * 4 + wv;
    u16x8v h = *(const u16x8v*)(sT + (size_t)row * 512 + lane * 8);
    float acc = 0.f;
#pragma unroll
    for (int i = 0; i < 8; ++i) acc += h2f(h[i]) * swu[lane * 8 + i];
#pragma unroll
    for (int m = 1; m < 64; m <<= 1) acc += __shfl_xor(acc, m);
    if (!lane) u[row] = acc;
}

// --------------------------------------------- GEMM (R12 2-phase engine) ----
#define EPI_F32       0
#define EPI_PLAIN_F16 2

__device__ __forceinline__ void stageA(
    const u16* __restrict__ g, int ldk, int i0, int k0, char* tile, int wv, int lane)
{
#pragma unroll
    for (int cc = 0; cc < 4; ++cc) {
        int chunk = (wv * 4 + cc) * 64 + lane;
        int row  = chunk >> 3;
        int slot = chunk & 7;
        int gc   = slot ^ (row & 7);
        const u16* gp = g + (size_t)(i0 + row) * ldk + (k0 + gc * 8);
        char* lp = tile + (size_t)(wv * 4 + cc) * 1024;
        __builtin_amdgcn_global_load_lds(
            (const __attribute__((address_space(1))) unsigned int*)gp,
            (__attribute__((address_space(3))) unsigned int*)lp, 16, 0, 0);
    }
}
__device__ __forceinline__ void stageB(
    const u16* __restrict__ g, int ldk, int j0, int k0, char* tile, int wv, int lane)
{
#pragma unroll
    for (int cc = 0; cc < 2; ++cc) {
        int chunk = (wv * 2 + cc) * 64 + lane;
        int row  = chunk >> 3;
        int slot = chunk & 7;
        int gc   = slot ^ (row & 7);
        const u16* gp = g + (size_t)(j0 + row) * ldk + (k0 + gc * 8);
        char* lp = tile + (size_t)(wv * 2 + cc) * 1024;
        __builtin_amdgcn_global_load_lds(
            (const __attribute__((address_space(1))) unsigned int*)gp,
            (__attribute__((address_space(3))) unsigned int*)lp, 16, 0, 0);
    }
}

template<int EPI>
__global__ void __launch_bounds__(512) gemm_bt(
    const u16* __restrict__ A_, const u16* __restrict__ B_,
    int K, int ldk, const float* __restrict__ bias,
    const float* __restrict__ jb, long jbZ,
    float* __restrict__ outF_, u16* __restrict__ outH_,
    int ldo, int zdiv,
    long aBatch, long aChunk, long bBatch, long bChunk, long oZ)
{
    __shared__ char smem[49152];                 // A: 32KB, B: 16KB

    unsigned swz = xcd_swz_flat();
    unsigned bx = swz % gridDim.x;
    unsigned rem = swz / gridDim.x;
    unsigned by = rem % gridDim.y;
    unsigned bz = rem / gridDim.y;

    int batch = bz / zdiv, chunk = bz % zdiv;
    const u16* A  = A_ + (size_t)batch * aBatch + (size_t)chunk * aChunk;
    const u16* Bm = B_ + (size_t)batch * bBatch + (size_t)chunk * bChunk;

    int i0 = by * 256, j0 = bx * 128;
    int tid = threadIdx.x, lane = tid & 63, wv = tid >> 6;
    int wr = wv >> 1, wc = wv & 1;
    int r15 = lane & 15, h4 = lane >> 4;

    f32x4 zero = {0.f, 0.f, 0.f, 0.f};
    f32x4 acc[4][4];
#pragma unroll
    for (int m = 0; m < 4; ++m)
#pragma unroll
        for (int n = 0; n < 4; ++n) acc[m][n] = zero;

    for (int k0 = 0; k0 < K; k0 += 64) {
        stageA(A, ldk, i0, k0, smem, wv, lane);
        stageB(Bm, ldk, j0, k0, smem + 32768, wv, lane);
        asm volatile("s_waitcnt vmcnt(0)" ::: "memory");
        __syncthreads();
#pragma unroll
        for (int ks = 0; ks < 2; ++ks) {
            f16x8 a[4], b[4];
#pragma unroll
            for (int m = 0; m < 4; ++m) {
                int row = wr * 64 + m * 16 + r15;
                int off = row * 128 + (((ks * 4 + h4) ^ (row & 7)) << 4);
                a[m] = *(const f16x8*)(smem + off);
            }
#pragma unroll
            for (int n = 0; n < 4; ++n) {
                int col = wc * 64 + n * 16 + r15;
                int off = col * 128 + (((ks * 4 + h4) ^ (col & 7)) << 4);
                b[n] = *(const f16x8*)(smem + 32768 + off);
            }
#pragma unroll
            for (int m = 0; m < 4; ++m)
#pragma unroll
                for (int n = 0; n < 4; ++n)
                    acc[m][n] = __builtin_amdgcn_mfma_f32_16x16x32_f16(a[m], b[n], acc[m][n], 0, 0, 0);
        }
        __syncthreads();
    }

    float* outF = outF_ ? outF_ + (size_t)bz * oZ : nullptr;
    u16* outH = outH_ ? outH_ + (size_t)bz * oZ : nullptr;
    const float* jbp = jb ? jb + (size_t)bz * jbZ : nullptr;

#pragma unroll
    for (int m = 0; m < 4; ++m)
#pragma unroll
        for (int n = 0; n < 4; ++n) {
            int ibase = i0 + wr * 64 + m * 16 + h4 * 4;
            int j = j0 + wc * 64 + n * 16 + r15;
#pragma unroll
            for (int r = 0; r < 4; ++r) {
                int i = ibase + r;
                float v = acc[m][n][r];
                if constexpr (EPI == EPI_PLAIN_F16) {
                    if (bias) v += bias[i];
                    if (jbp) v += jbp[j];
                    outH[(size_t)i * ldo + j] = f2h(v);
                } else {
                    outF[(size_t)i * ldo + j] = v;
                }
            }
        }
}

// ---------------- 256x256-tile 2-phase engine (logits + PV variants) -------
__device__ __forceinline__ void stage256(
    const u16* __restrict__ g, int ldk, int r0, int k0, char* tile, int wv, int lane)
{
#pragma unroll
    for (int cc = 0; cc < 4; ++cc) {
        int grp = cc * 8 + wv;
        int chunk = grp * 64 + lane;
        int row  = chunk >> 3;
        int slot = chunk & 7;
        int gc   = slot ^ (row & 7);
        const u16* gp = g + (size_t)(r0 + row) * ldk + (k0 + gc * 8);
        char* lp = tile + (size_t)grp * 1024;
        __builtin_amdgcn_global_load_lds(
            (const __attribute__((address_space(1))) unsigned int*)gp,
            (__attribute__((address_space(3))) unsigned int*)lp, 16, 0, 0);
    }
}

__global__ void __launch_bounds__(512) glogits256(
    const u16* __restrict__ A_, const u16* __restrict__ B_,
    const float* __restrict__ jb_, u16* __restrict__ outH_,
    long aZ, long bZ, long jbZ, long oZ)
{
    extern __shared__ char smem[];               // A 32KB | B 32KB

    unsigned swz = xcd_swz_flat();
    unsigned bx = swz % gridDim.x;
    unsigned rem = swz / gridDim.x;
    unsigned by = rem % gridDim.y;
    unsigned bz = rem / gridDim.y;

    const u16* A  = A_ + (size_t)bz * aZ;
    const u16* Bm = B_ + (size_t)bz * bZ;

    int i0 = by * 256, j0 = bx * 256;
    int tid = threadIdx.x, lane = tid & 63, wv = tid >> 6;
    int wr = wv >> 2, wc = wv & 3;               // 2M x 4N waves, 128x64 each
    int r15 = lane & 15, h4 = lane >> 4;

    f32x4 zero = {0.f, 0.f, 0.f, 0.f};
    f32x4 acc[8][4];
#pragma unroll
    for (int m = 0; m < 8; ++m)
#pragma unroll
        for (int n = 0; n < 4; ++n) acc[m][n] = zero;

    for (int k0 = 0; k0 < 512; k0 += 64) {
        stage256(A,  512, i0, k0, smem,         wv, lane);
        stage256(Bm, 512, j0, k0, smem + 32768, wv, lane);
        asm volatile("s_waitcnt vmcnt(0)" ::: "memory");
        __syncthreads();
#pragma unroll
        for (int ks = 0; ks < 2; ++ks) {
            f16x8 a[8], b[4];
#pragma unroll
            for (int m = 0; m < 8; ++m) {
                int row = wr * 128 + m * 16 + r15;
                int off = row * 128 + (((ks * 4 + h4) ^ (row & 7)) << 4);
                a[m] = *(const f16x8*)(smem + off);
            }
#pragma unroll
            for (int n = 0; n < 4; ++n) {
                int col = wc * 64 + n * 16 + r15;
                int off = col * 128 + (((ks * 4 + h4) ^ (col & 7)) << 4);
                b[n] = *(const f16x8*)(smem + 32768 + off);
            }
#pragma unroll
            for (int m = 0; m < 8; ++m)
#pragma unroll
                for (int n = 0; n < 4; ++n)
                    acc[m][n] = __builtin_amdgcn_mfma_f32_16x16x32_f16(a[m], b[n], acc[m][n], 0, 0, 0);
        }
        __syncthreads();
    }

    u16* outH = outH_ + (size_t)bz * oZ;
    const float* jbp = jb_ + (size_t)bz * jbZ;
#pragma unroll
    for (int m = 0; m < 8; ++m)
#pragma unroll
        for (int n = 0; n < 4; ++n) {
            int ibase = i0 + wr * 128 + m * 16 + h4 * 4;
            int j = j0 + wc * 64 + n * 16 + r15;
            float ub = jbp[j];
#pragma unroll
            for (int r = 0; r < 4; ++r) {
                int i = ibase + r;
                outH[(size_t)i * 4096 + j] = f2h(acc[m][n][r] + ub);
            }
        }
}

// PV on the 256^2 engine: out[z][o,n] = sum_k A[o, k] * P[n, k] over K=1024
// chunk; z: batch = z>>2, chunk = z&3. ldk = 4096 for both operands.
__global__ void __launch_bounds__(512) pv256(
    const u16* __restrict__ A_, const u16* __restrict__ B_,
    u16* __restrict__ outH_,
    long aBatch, long aChunk, long bBatch, long bChunk, long oZ)
{
    extern __shared__ char smem[];               // A 32KB | B 32KB

    unsigned swz = xcd_swz_flat();
    unsigned bx = swz % gridDim.x;
    unsigned rem = swz / gridDim.x;
    unsigned by = rem % gridDim.y;
    unsigned bz = rem / gridDim.y;

    int batch = bz >> 2, chunk = bz & 3;
    const u16* A  = A_ + (size_t)batch * aBatch + (size_t)chunk * aChunk;
    const u16* Bm = B_ + (size_t)batch * bBatch + (size_t)chunk * bChunk;

    int i0 = by * 256, j0 = bx * 256;
    int tid = threadIdx.x, lane = tid & 63, wv = tid >> 6;
    int wr = wv >> 2, wc = wv & 3;
    int r15 = lane & 15, h4 = lane >> 4;

    f32x4 zero = {0.f, 0.f, 0.f, 0.f};
    f32x4 acc[8][4];
#pragma unroll
    for (int m = 0; m < 8; ++m)
#pragma unroll
        for (int n = 0; n < 4; ++n) acc[m][n] = zero;

    for (int k0 = 0; k0 < 1024; k0 += 64) {
        stage256(A,  4096, i0, k0, smem,         wv, lane);
        stage256(Bm, 4096, j0, k0, smem + 32768, wv, lane);
        asm volatile("s_waitcnt vmcnt(0)" ::: "memory");
        __syncthreads();
#pragma unroll
        for (int ks = 0; ks < 2; ++ks) {
            f16x8 a[8], b[4];
#pragma unroll
            for (int m = 0; m < 8; ++m) {
                int row = wr * 128 + m * 16 + r15;
                int off = row * 128 + (((ks * 4 + h4) ^ (row & 7)) << 4);
                a[m] = *(const f16x8*)(smem + off);
            }
#pragma unroll
            for (int n = 0; n < 4; ++n) {
                int col = wc * 64 + n * 16 + r15;
                int off = col * 128 + (((ks * 4 + h4) ^ (col & 7)) << 4);
                b[n] = *(const f16x8*)(smem + 32768 + off);
            }
#pragma unroll
            for (int m = 0; m < 8; ++m)
#pragma unroll
                for (int n = 0; n < 4; ++n)
                    acc[m][n] = __builtin_amdgcn_mfma_f32_16x16x32_f16(a[m], b[n], acc[m][n], 0, 0, 0);
        }
        __syncthreads();
    }

    u16* outH = outH_ + (size_t)bz * oZ;
#pragma unroll
    for (int m = 0; m < 8; ++m)
#pragma unroll
        for (int n = 0; n < 4; ++n) {
            int ibase = i0 + wr * 128 + m * 16 + h4 * 4;
            int j = j0 + wc * 64 + n * 16 + r15;
#pragma unroll
            for (int r = 0; r < 4; ++r) {
                int i = ibase + r;
                outH[(size_t)i * 4096 + j] = f2h(acc[m][n][r]);
            }
        }
}

// ------------------------------------------------------ softmax (f16) ----
__global__ void __launch_bounds__(256) softmax16(u16* __restrict__ LP)
{
    u16x8v* row = (u16x8v*)(LP + (size_t)blockIdx.x * 4096);
    int t = threadIdx.x, lane = t & 63, wv = t >> 6;
    u16x8v ca = row[t], cb = row[t + 256];
    float va[8], vb[8];
    float mx = -3.4e38f;
#pragma unroll
    for (int i = 0; i < 8; ++i) {
        va[i] = h2f(ca[i]); vb[i] = h2f(cb[i]);
        mx = fmaxf(mx, fmaxf(va[i], vb[i]));
    }
#pragma unroll
    for (int m = 1; m < 64; m <<= 1) mx = fmaxf(mx, __shfl_xor(mx, m));
    __shared__ float sM[4], sS[4];
    if (!lane) sM[wv] = mx;
    __syncthreads();
    mx = fmaxf(fmaxf(sM[0], sM[1]), fmaxf(sM[2], sM[3]));
    float sum = 0.f;
#pragma unroll
    for (int i = 0; i < 8; ++i) {
        va[i] = __expf(va[i] - mx);
        vb[i] = __expf(vb[i] - mx);
        sum += va[i] + vb[i];
    }
#pragma unroll
    for (int m = 1; m < 64; m <<= 1) sum += __shfl_xor(sum, m);
    if (!lane) sS[wv] = sum;
    __syncthreads();
    sum = sS[0] + sS[1] + sS[2] + sS[3];
    float inv = 1.0f / sum;
    u16x8v oa, ob;
#pragma unroll
    for (int i = 0; i < 8; ++i) {
        oa[i] = f2h(va[i] * inv);
        ob[i] = f2h(vb[i] * inv);
    }
    row[t] = oa; row[t + 256] = ob;
}

// -------------------------------------- split-K reduce + residual + v -----
__global__ void __launch_bounds__(256) reduce4resid(
    const u16* __restrict__ part, const float* __restrict__ xr,
    const float* __restrict__ v, float* __restrict__ out)
{
    const size_t PLANE = 2097152;
    int b = blockIdx.y;
    size_t g8 = ((size_t)blockIdx.x * 256 + threadIdx.x) * 8;
    const u16* p0 = part + (size_t)b * 4 * PLANE + g8;
    float acc[8] = {0.f, 0.f, 0.f, 0.f, 0.f, 0.f, 0.f, 0.f};
#pragma unroll
    for (int k = 0; k < 4; ++k) {
        u16x8v h = *(const u16x8v*)(p0 + (size_t)k * PLANE);
#pragma unroll
        for (int i = 0; i < 8; ++i) acc[i] += h2f(h[i]);
    }
    const float4* xv = (const float4*)(xr + (size_t)b * PLANE + g8);
    float4 x0 = xv[0], x1 = xv[1];
    float vc = v[g8 >> 12];
    float4 o0, o1;
    o0.x = acc[0] + x0.x + vc; o0.y = acc[1] + x0.y + vc;
    o0.z = acc[2] + x0.z + vc; o0.w = acc[3] + x0.w + vc;
    o1.x = acc[4] + x1.x + vc; o1.y = acc[5] + x1.y + vc;
    o1.z = acc[6] + x1.z + vc; o1.w = acc[7] + x1.w + vc;
    float4* op = (float4*)(out + (size_t)b * PLANE + g8);
    op[0] = o0; op[1] = o1;
}

// -------------------------------------------------------------- launch ----
extern "C" void kernel_launch(void* const* d_in, const int* in_sizes, int n_in,
                              void* d_out, int out_size, void* d_ws, size_t ws_size,
                              hipStream_t stream)
{
    const float* c   = (const float*)d_in[0];
    const float* s   = (const float*)d_in[1];
    const float* x   = (const float*)d_in[2];
    const float* c_w = (const float*)d_in[3];
    const float* c_b = (const float*)d_in[4];
    const float* s_w = (const float*)d_in[5];
    const float* s_b = (const float*)d_in[6];
    const float* i_w = (const float*)d_in[7];
    const float* i_b = (const float*)d_in[8];
    const float* o_w = (const float*)d_in[9];
    const float* o_b = (const float*)d_in[10];
    float* out = (float*)d_out;
    char* ws = (char*)d_ws;

    const int B = 4, C = 512, N = 4096;
    const size_t NC = (size_t)N * C;
    const size_t W2 = (size_t)C * C;
    const size_t NN = (size_t)N * N;
    const int SMEM256 = 65536;

    size_t off = 0;
    auto alloc = [&](size_t bytes) { size_t o = off; off += (bytes + 255) & ~(size_t)255; return o; };

    size_t o_meanC = alloc((size_t)B * C * 4);
    size_t o_rstdC = alloc((size_t)B * C * 4);
    size_t o_meanS = alloc((size_t)B * C * 4);
    size_t o_rstdS = alloc((size_t)B * C * 4);
    size_t o_cwT = alloc(W2 * 2);
    size_t o_swT = alloc(W2 * 2);
    size_t o_iwT = alloc(W2 * 2);
    size_t o_ow  = alloc(W2 * 2);
    size_t o_G   = alloc(W2 * 2);            // G[a,l] = c_w^T s_w
    size_t o_W   = alloc(W2 * 2);            // W = o_w @ i_w
    size_t o_Gb  = alloc((size_t)B * W2 * 2);// per-batch Gb = diag(rC)·G·diag(rS)
    size_t o_v   = alloc((size_t)C * 4);
    size_t o_wu  = alloc((size_t)C * 4);
    size_t o_wb  = alloc((size_t)B * C * 4); // per-batch rowdot vector
    size_t o_u   = alloc((size_t)B * N * 4);
    size_t o_pS  = alloc((size_t)8 * 512 * 128 * 4);  // stat partials
    size_t o_pQ  = alloc((size_t)8 * 512 * 128 * 4);
    size_t o_cT  = alloc(B * NC * 2);        // raw c transposed [B,N,C] f16
    size_t o_sT  = alloc(B * NC * 2);        // raw s transposed (PV + sg + rowdot)
    size_t o_sgT = alloc(B * NC * 2);        // sg[m,a] = Gb_b @ sT
    size_t o_sW  = alloc(B * NC * 2);        // sW[o,m] = W @ sT
    size_t o_P   = alloc(2 * NN * 2);        // PAIR logits/P f16 (67MB)
    size_t o_pt  = alloc(8 * NC * 2);        // pair split-K4 partials f16

    if (ws_size < off) {
        (void)hipMemsetAsync(d_out, 0, (size_t)out_size * 4, stream);
        return;
    }

    float* meanC = (float*)(ws + o_meanC);
    float* rstdC = (float*)(ws + o_rstdC);
    float* meanS = (float*)(ws + o_meanS);
    float* rstdS = (float*)(ws + o_rstdS);
    u16* cwT = (u16*)(ws + o_cwT);
    u16* swT = (u16*)(ws + o_swT);
    u16* iwT = (u16*)(ws + o_iwT);
    u16* ow  = (u16*)(ws + o_ow);
    u16* Gf  = (u16*)(ws + o_G);
    u16* Wf  = (u16*)(ws + o_W);
    u16* Gb  = (u16*)(ws + o_Gb);
    float* vb = (float*)(ws + o_v);
    float* wu = (float*)(ws + o_wu);
    float* wb = (float*)(ws + o_wb);
    float* ub = (float*)(ws + o_u);
    float* pS = (float*)(ws + o_pS);
    float* pQ = (float*)(ws + o_pQ);
    u16* cT  = (u16*)(ws + o_cT);
    u16* sT  = (u16*)(ws + o_sT);
    u16* sgT = (u16*)(ws + o_sgT);
    u16* sW  = (u16*)(ws + o_sW);
    u16* Pb  = (u16*)(ws + o_P);
    u16* partH = (u16*)(ws + o_pt);

    // 1) pack raw transposed f16 + stat partials (single fp32 pass)
    packstat<<<dim3(N / 32, C / 32, 8), dim3(32, 8), 0, stream>>>(
        c, s, cT, sT, pS, pQ);
    // 2) stats reduce -> mean/rstd per (tensor,batch,channel)
    statreduce<<<dim3(8 * 512), 64, 0, stream>>>(pS, pQ, meanC, rstdC, meanS, rstdS);
    // 3) weight preps
    prep_kernel<<<dim3(16, 16, 4), dim3(32, 8), 0, stream>>>(
        c_w, s_w, i_w, o_w, cwT, swT, iwT, ow);
    bias_prep<<<dim3(4), 256, 0, stream>>>(o_w, i_b, o_b, s_w, c_b, vb, wu);
    // G[a,l] = c_w^T s_w  and  W[o,c] = o_w i_w  in one dispatch
    gemm_bt<EPI_PLAIN_F16><<<dim3(4, 2, 2), 512, 0, stream>>>(
        cwT, swT, 512, 512, nullptr, nullptr, 0, nullptr, Gf, 512, 1,
        (long)(3 * W2), 0, (long)W2, 0, (long)W2);
    // 4) fold instance-norm into weights: Gb_b, wb_b (wave-parallel)
    wb_kernel<<<dim3(B * 512 / 4), 256, 0, stream>>>(Gf, wu, meanC, rstdC, rstdS, wb);
    gbscale<<<dim3(128, B), 256, 0, stream>>>(Gf, rstdC, rstdS, Gb);
    // 5) sgT[m,a] = sum_l sT[m,l]*Gb_b[a,l]  (natural [m,a])
    gemm_bt<EPI_PLAIN_F16><<<dim3(4, 16, B), 512, 0, stream>>>(
        sT, Gb, 512, 512, nullptr, nullptr, 0, nullptr, sgT, 512, 1,
        (long)NC, 0, (long)W2, 0, (long)NC);
    // 6) sW[o,m] = sum_c W[o,c]*sT[m,c]
    gemm_bt<EPI_PLAIN_F16><<<dim3(32, 2, B), 512, 0, stream>>>(
        Wf, sT, 512, 512, nullptr, nullptr, 0, nullptr, sW, 4096, 1,
        0, 0, (long)NC, 0, (long)NC);
    // 7) u[b,m] = sum_l sT[b,m,l]*wb[b,l]
    rowdot_kernel<<<dim3(B * N / 4), 256, 0, stream>>>(sT, wb, ub);
    // 8) attention in batch PAIRS — 256^2 engine for logits AND PV
    for (int pb0 = 0; pb0 < B; pb0 += 2) {
        glogits256<<<dim3(16, 16, 2), 512, SMEM256, stream>>>(
            cT + (size_t)pb0 * NC, sgT + (size_t)pb0 * NC,
            ub + (size_t)pb0 * N, Pb,
            (long)NC, (long)NC, (long)N, (long)NN);
        softmax16<<<dim3(2 * N), 256, 0, stream>>>(Pb);
        // PV: out[z][o,n] = sum_m sW[o,m]*P[n,m]; split-K4, 256^2 tile
        pv256<<<dim3(16, 2, 8), 512, SMEM256, stream>>>(
            sW + (size_t)pb0 * NC, Pb, partH,
            (long)NC, 1024L, (long)NN, 1024L, (long)NC);
        reduce4resid<<<dim3((int)(NC / 2048), 2), 256, 0, stream>>>(
            partH, x + (size_t)pb0 * NC, vb, out + (size_t)pb0 * NC);
    }
}

// Round 23
// 336.399 us; speedup vs baseline: 1.0508x; 1.0508x over previous
//
#include <hip/hip_runtime.h>

typedef unsigned short u16;
typedef _Float16 f16x8 __attribute__((ext_vector_type(8)));
typedef float f32x4 __attribute__((ext_vector_type(4)));
typedef u16 u16x4 __attribute__((ext_vector_type(4)));
typedef u16 u16x8v __attribute__((ext_vector_type(8)));

__device__ __forceinline__ u16 f2h(float f) {
    _Float16 h = (_Float16)f;
    return __builtin_bit_cast(u16, h);
}
__device__ __forceinline__ float h2f(u16 u) {
    return (float)__builtin_bit_cast(_Float16, u);
}

// XCD-aware bijective block remap (T1). Requires total blocks % 8 == 0.
__device__ __forceinline__ unsigned xcd_swz_flat()
{
    unsigned total = gridDim.x * gridDim.y * gridDim.z;
    unsigned flat = (blockIdx.z * gridDim.y + blockIdx.y) * gridDim.x + blockIdx.x;
    return (flat & 7) * (total >> 3) + (flat >> 3);
}

// ----------------------------------------- pack (raw, transposed) + stats ----
__global__ void __launch_bounds__(256) packstat(
    const float* __restrict__ c, const float* __restrict__ s,
    u16* __restrict__ cT, u16* __restrict__ sT,
    float* __restrict__ pS, float* __restrict__ pQ)
{
    __shared__ float tile[32][33];
    int z = blockIdx.z;
    bool isS = z >= 4;
    int b = z & 3;
    const float* src = isS ? s : c;
    u16* dst = isS ? sT : cT;
    int n0 = blockIdx.x * 32, c0 = blockIdx.y * 32;
    int tx = threadIdx.x, ty = threadIdx.y;
    const float* sbp = src + ((size_t)b * 512 + c0) * 4096 + n0;
#pragma unroll
    for (int it = 0; it < 4; ++it) {
        int cc = ty + it * 8;
        tile[cc][tx] = sbp[(size_t)cc * 4096 + tx];
    }
    __syncthreads();
    size_t obase = ((size_t)b * 4096 + n0) * 512 + c0;
#pragma unroll
    for (int it = 0; it < 4; ++it) {
        int r = ty + it * 8;
        dst[obase + (size_t)r * 512 + tx] = f2h(tile[tx][r]);
    }
    if (ty == 0) {
        float sm = 0.f, sq = 0.f;
#pragma unroll
        for (int n = 0; n < 32; ++n) {
            float v = tile[tx][n];
            sm += v; sq += v * v;
        }
        size_t idx = ((size_t)z * 512 + c0 + tx) * 128 + blockIdx.x;
        pS[idx] = sm; pQ[idx] = sq;
    }
}

// -------------------------------------------------------- stats reduce ----
__global__ void __launch_bounds__(64) statreduce(
    const float* __restrict__ pS, const float* __restrict__ pQ,
    float* __restrict__ mC, float* __restrict__ rC,
    float* __restrict__ mS, float* __restrict__ rS)
{
    int row = blockIdx.x;            // z*512 + ch
    int lane = threadIdx.x;
    const float* ps = pS + (size_t)row * 128;
    const float* pq = pQ + (size_t)row * 128;
    float sm = ps[lane] + ps[lane + 64];
    float sq = pq[lane] + pq[lane + 64];
#pragma unroll
    for (int m = 1; m < 64; m <<= 1) {
        sm += __shfl_xor(sm, m);
        sq += __shfl_xor(sq, m);
    }
    if (lane == 0) {
        float mean = sm * (1.0f / 4096.0f);
        float var = (sq - 4096.0f * mean * mean) * (1.0f / 4095.0f);
        float rstd = rsqrtf(var + 1e-5f);
        int z = row >> 9, ch = row & 511;
        int b = z & 3;
        if (z < 4) { mC[b * 512 + ch] = mean; rC[b * 512 + ch] = rstd; }
        else       { mS[b * 512 + ch] = mean; rS[b * 512 + ch] = rstd; }
    }
}

// ------------------------------------------------- fused weight prep ------
__global__ void __launch_bounds__(256) prep_kernel(
    const float* __restrict__ c_w, const float* __restrict__ s_w,
    const float* __restrict__ i_w, const float* __restrict__ o_w,
    u16* __restrict__ cwT, u16* __restrict__ swT,
    u16* __restrict__ iwT, u16* __restrict__ ow)
{
    int z = blockIdx.z;
    int tx = threadIdx.x, ty = threadIdx.y;
    if (z == 3) {
        size_t base = ((size_t)(blockIdx.y * 16 + blockIdx.x) * 256 +
                       (ty * 32 + tx)) * 4;
        float4 v = *(const float4*)(o_w + base);
        u16x4 o;
        o[0] = f2h(v.x); o[1] = f2h(v.y); o[2] = f2h(v.z); o[3] = f2h(v.w);
        *(u16x4*)(ow + base) = o;
        return;
    }
    const float* w = (z == 0) ? c_w : (z == 1) ? s_w : i_w;
    u16* wT = (z == 0) ? cwT : (z == 1) ? swT : iwT;
    __shared__ float tile[32][33];
    int c0 = blockIdx.x * 32, k0 = blockIdx.y * 32;
#pragma unroll
    for (int it = 0; it < 4; ++it) {
        int kk = ty + it * 8;
        tile[kk][tx] = w[(size_t)(k0 + kk) * 512 + c0 + tx];
    }
    __syncthreads();
#pragma unroll
    for (int it = 0; it < 4; ++it) {
        int r = ty + it * 8;
        wT[(size_t)(c0 + r) * 512 + k0 + tx] = f2h(tile[tx][r]);
    }
}

// ------------------------------------------------- fused bias prep --------
__global__ void __launch_bounds__(256) bias_prep(
    const float* __restrict__ o_w, const float* __restrict__ i_b,
    const float* __restrict__ o_b, const float* __restrict__ s_w,
    const float* __restrict__ c_b, float* __restrict__ v,
    float* __restrict__ wu)
{
    __shared__ float buf[512];
    int t = threadIdx.x;
    bool isWu = blockIdx.x >= 2;
    const float* vec = isWu ? c_b : i_b;
    buf[t] = vec[t]; buf[t + 256] = vec[t + 256];
    __syncthreads();
    int o = (blockIdx.x & 1) * 256 + t;
    if (!isWu) {
        float acc = o_b[o];
        const float* row = o_w + (size_t)o * 512;
        for (int k = 0; k < 512; ++k) acc += row[k] * buf[k];
        v[o] = acc;
    } else {
        float acc = 0.f;
        for (int k = 0; k < 512; ++k) acc += buf[k] * s_w[(size_t)k * 512 + o];
        wu[o] = acc;
    }
}

// -------- wb[b,l] = (wu[l] - sum_a mC·rC·G[a,l]) · rS[b,l]  (wave/output) --
__global__ void __launch_bounds__(256) wb_kernel(
    const u16* __restrict__ G, const float* __restrict__ wu,
    const float* __restrict__ mC, const float* __restrict__ rC,
    const float* __restrict__ rS, float* __restrict__ wb)
{
    int t = threadIdx.x, lane = t & 63, wv = t >> 6;
    int gid = blockIdx.x * 4 + wv;       // over B*512
    int b = gid >> 9, l = gid & 511;
    float acc = 0.f;
#pragma unroll
    for (int i = 0; i < 8; ++i) {
        int a = lane * 8 + i;
        acc += mC[b * 512 + a] * rC[b * 512 + a] * h2f(G[(size_t)a * 512 + l]);
    }
#pragma unroll
    for (int m = 1; m < 64; m <<= 1) acc += __shfl_xor(acc, m);
    if (!lane) wb[b * 512 + l] = (wu[l] - acc) * rS[b * 512 + l];
}

// ---------------------- Gb[b][a][l] = rC[b,a] · G[a,l] · rS[b,l]  (f16) ----
__global__ void __launch_bounds__(256) gbscale(
    const u16* __restrict__ G, const float* __restrict__ rC,
    const float* __restrict__ rS, u16* __restrict__ Gb)
{
    int b = blockIdx.y;
    size_t idx = ((size_t)blockIdx.x * 256 + threadIdx.x) * 8; // over 512*512
    int a = (int)(idx >> 9), l0 = (int)(idx & 511);
    float ra = rC[b * 512 + a];
    u16x8v g = *(const u16x8v*)(G + idx);
    const float4* q4 = (const float4*)(rS + b * 512 + l0);
    float4 q0 = q4[0], q1 = q4[1];
    u16x8v o;
    o[0] = f2h(ra * h2f(g[0]) * q0.x); o[1] = f2h(ra * h2f(g[1]) * q0.y);
    o[2] = f2h(ra * h2f(g[2]) * q0.z); o[3] = f2h(ra * h2f(g[3]) * q0.w);
    o[4] = f2h(ra * h2f(g[4]) * q1.x); o[5] = f2h(ra * h2f(g[5]) * q1.y);
    o[6] = f2h(ra * h2f(g[6]) * q1.z); o[7] = f2h(ra * h2f(g[7]) * q1.w);
    *(u16x8v*)(Gb + (size_t)b * 262144 + idx) = o;
}

// u[b,r] = sum_l sT[b,r,l] * wb[b,l]
__global__ void __launch_bounds__(256) rowdot_kernel(
    const u16* __restrict__ sT, const float* __restrict__ wb,
    float* __restrict__ u)
{
    __shared__ float swu[512];
    int t = threadIdx.x;
    const float* wbb = wb + (size_t)(blockIdx.x >> 10) * 512;
    swu[t] = wbb[t]; swu[t + 256] = wbb[t + 256];
    __syncthreads();
    int lane = t & 63, wv = t >> 6;
    int row = blockIdx.x * 4 + wv;
    u16x8v h = *(const u16x8v*)(sT + (size_t)row * 512 + lane * 8);
    float acc = 0.f;
#pragma unroll
    for (int i = 0; i < 8; ++i) acc += h2f(h[i]) * swu[lane * 8 + i];
#pragma unroll
    for (int m = 1; m < 64; m <<= 1) acc += __shfl_xor(acc, m);
    if (!lane) u[row] = acc;
}

// --------------------------------------------- GEMM (R12 2-phase engine) ----
#define EPI_F32       0
#define EPI_PLAIN_F16 2

__device__ __forceinline__ void stageA(
    const u16* __restrict__ g, int ldk, int i0, int k0, char* tile, int wv, int lane)
{
#pragma unroll
    for (int cc = 0; cc < 4; ++cc) {
        int chunk = (wv * 4 + cc) * 64 + lane;
        int row  = chunk >> 3;
        int slot = chunk & 7;
        int gc   = slot ^ (row & 7);
        const u16* gp = g + (size_t)(i0 + row) * ldk + (k0 + gc * 8);
        char* lp = tile + (size_t)(wv * 4 + cc) * 1024;
        __builtin_amdgcn_global_load_lds(
            (const __attribute__((address_space(1))) unsigned int*)gp,
            (__attribute__((address_space(3))) unsigned int*)lp, 16, 0, 0);
    }
}
__device__ __forceinline__ void stageB(
    const u16* __restrict__ g, int ldk, int j0, int k0, char* tile, int wv, int lane)
{
#pragma unroll
    for (int cc = 0; cc < 2; ++cc) {
        int chunk = (wv * 2 + cc) * 64 + lane;
        int row  = chunk >> 3;
        int slot = chunk & 7;
        int gc   = slot ^ (row & 7);
        const u16* gp = g + (size_t)(j0 + row) * ldk + (k0 + gc * 8);
        char* lp = tile + (size_t)(wv * 2 + cc) * 1024;
        __builtin_amdgcn_global_load_lds(
            (const __attribute__((address_space(1))) unsigned int*)gp,
            (__attribute__((address_space(3))) unsigned int*)lp, 16, 0, 0);
    }
}

template<int EPI>
__global__ void __launch_bounds__(512) gemm_bt(
    const u16* __restrict__ A_, const u16* __restrict__ B_,
    int K, int ldk, const float* __restrict__ bias,
    const float* __restrict__ jb, long jbZ,
    float* __restrict__ outF_, u16* __restrict__ outH_,
    int ldo, int zdiv,
    long aBatch, long aChunk, long bBatch, long bChunk, long oZ)
{
    __shared__ char smem[49152];                 // A: 32KB, B: 16KB

    unsigned swz = xcd_swz_flat();
    unsigned bx = swz % gridDim.x;
    unsigned rem = swz / gridDim.x;
    unsigned by = rem % gridDim.y;
    unsigned bz = rem / gridDim.y;

    int batch = bz / zdiv, chunk = bz % zdiv;
    const u16* A  = A_ + (size_t)batch * aBatch + (size_t)chunk * aChunk;
    const u16* Bm = B_ + (size_t)batch * bBatch + (size_t)chunk * bChunk;

    int i0 = by * 256, j0 = bx * 128;
    int tid = threadIdx.x, lane = tid & 63, wv = tid >> 6;
    int wr = wv >> 1, wc = wv & 1;
    int r15 = lane & 15, h4 = lane >> 4;

    f32x4 zero = {0.f, 0.f, 0.f, 0.f};
    f32x4 acc[4][4];
#pragma unroll
    for (int m = 0; m < 4; ++m)
#pragma unroll
        for (int n = 0; n < 4; ++n) acc[m][n] = zero;

    for (int k0 = 0; k0 < K; k0 += 64) {
        stageA(A, ldk, i0, k0, smem, wv, lane);
        stageB(Bm, ldk, j0, k0, smem + 32768, wv, lane);
        asm volatile("s_waitcnt vmcnt(0)" ::: "memory");
        __syncthreads();
#pragma unroll
        for (int ks = 0; ks < 2; ++ks) {
            f16x8 a[4], b[4];
#pragma unroll
            for (int m = 0; m < 4; ++m) {
                int row = wr * 64 + m * 16 + r15;
                int off = row * 128 + (((ks * 4 + h4) ^ (row & 7)) << 4);
                a[m] = *(const f16x8*)(smem + off);
            }
#pragma unroll
            for (int n = 0; n < 4; ++n) {
                int col = wc * 64 + n * 16 + r15;
                int off = col * 128 + (((ks * 4 + h4) ^ (col & 7)) << 4);
                b[n] = *(const f16x8*)(smem + 32768 + off);
            }
#pragma unroll
            for (int m = 0; m < 4; ++m)
#pragma unroll
                for (int n = 0; n < 4; ++n)
                    acc[m][n] = __builtin_amdgcn_mfma_f32_16x16x32_f16(a[m], b[n], acc[m][n], 0, 0, 0);
        }
        __syncthreads();
    }

    float* outF = outF_ ? outF_ + (size_t)bz * oZ : nullptr;
    u16* outH = outH_ ? outH_ + (size_t)bz * oZ : nullptr;
    const float* jbp = jb ? jb + (size_t)bz * jbZ : nullptr;

#pragma unroll
    for (int m = 0; m < 4; ++m)
#pragma unroll
        for (int n = 0; n < 4; ++n) {
            int ibase = i0 + wr * 64 + m * 16 + h4 * 4;
            int j = j0 + wc * 64 + n * 16 + r15;
#pragma unroll
            for (int r = 0; r < 4; ++r) {
                int i = ibase + r;
                float v = acc[m][n][r];
                if constexpr (EPI == EPI_PLAIN_F16) {
                    if (bias) v += bias[i];
                    if (jbp) v += jbp[j];
                    outH[(size_t)i * ldo + j] = f2h(v);
                } else {
                    outF[(size_t)i * ldo + j] = v;
                }
            }
        }
}

// ------------------------- logits GEMM, 256x256 tile, 2-phase --------------
__device__ __forceinline__ void stage256(
    const u16* __restrict__ g, int r0, int k0, char* tile, int wv, int lane)
{
#pragma unroll
    for (int cc = 0; cc < 4; ++cc) {
        int grp = cc * 8 + wv;
        int chunk = grp * 64 + lane;
        int row  = chunk >> 3;
        int slot = chunk & 7;
        int gc   = slot ^ (row & 7);
        const u16* gp = g + (size_t)(r0 + row) * 512 + (k0 + gc * 8);
        char* lp = tile + (size_t)grp * 1024;
        __builtin_amdgcn_global_load_lds(
            (const __attribute__((address_space(1))) unsigned int*)gp,
            (__attribute__((address_space(3))) unsigned int*)lp, 16, 0, 0);
    }
}

__global__ void __launch_bounds__(512) glogits256(
    const u16* __restrict__ A_, const u16* __restrict__ B_,
    const float* __restrict__ jb_, u16* __restrict__ outH_,
    long aZ, long bZ, long jbZ, long oZ)
{
    extern __shared__ char smem[];               // A 32KB | B 32KB

    unsigned swz = xcd_swz_flat();
    unsigned bx = swz % gridDim.x;
    unsigned rem = swz / gridDim.x;
    unsigned by = rem % gridDim.y;
    unsigned bz = rem / gridDim.y;

    const u16* A  = A_ + (size_t)bz * aZ;
    const u16* Bm = B_ + (size_t)bz * bZ;

    int i0 = by * 256, j0 = bx * 256;
    int tid = threadIdx.x, lane = tid & 63, wv = tid >> 6;
    int wr = wv >> 2, wc = wv & 3;               // 2M x 4N waves, 128x64 each
    int r15 = lane & 15, h4 = lane >> 4;

    f32x4 zero = {0.f, 0.f, 0.f, 0.f};
    f32x4 acc[8][4];
#pragma unroll
    for (int m = 0; m < 8; ++m)
#pragma unroll
        for (int n = 0; n < 4; ++n) acc[m][n] = zero;

    for (int k0 = 0; k0 < 512; k0 += 64) {
        stage256(A,  i0, k0, smem,         wv, lane);
        stage256(Bm, j0, k0, smem + 32768, wv, lane);
        asm volatile("s_waitcnt vmcnt(0)" ::: "memory");
        __syncthreads();
#pragma unroll
        for (int ks = 0; ks < 2; ++ks) {
            f16x8 a[8], b[4];
#pragma unroll
            for (int m = 0; m < 8; ++m) {
                int row = wr * 128 + m * 16 + r15;
                int off = row * 128 + (((ks * 4 + h4) ^ (row & 7)) << 4);
                a[m] = *(const f16x8*)(smem + off);
            }
#pragma unroll
            for (int n = 0; n < 4; ++n) {
                int col = wc * 64 + n * 16 + r15;
                int off = col * 128 + (((ks * 4 + h4) ^ (col & 7)) << 4);
                b[n] = *(const f16x8*)(smem + 32768 + off);
            }
#pragma unroll
            for (int m = 0; m < 8; ++m)
#pragma unroll
                for (int n = 0; n < 4; ++n)
                    acc[m][n] = __builtin_amdgcn_mfma_f32_16x16x32_f16(a[m], b[n], acc[m][n], 0, 0, 0);
        }
        __syncthreads();
    }

    u16* outH = outH_ + (size_t)bz * oZ;
    const float* jbp = jb_ + (size_t)bz * jbZ;
#pragma unroll
    for (int m = 0; m < 8; ++m)
#pragma unroll
        for (int n = 0; n < 4; ++n) {
            int ibase = i0 + wr * 128 + m * 16 + h4 * 4;
            int j = j0 + wc * 64 + n * 16 + r15;
            float ub = jbp[j];
#pragma unroll
            for (int r = 0; r < 4; ++r) {
                int i = ibase + r;
                outH[(size_t)i * 4096 + j] = f2h(acc[m][n][r] + ub);
            }
        }
}

// ------------------------------------------------------ softmax (f16) ----
__global__ void __launch_bounds__(256) softmax16(u16* __restrict__ LP)
{
    u16x8v* row = (u16x8v*)(LP + (size_t)blockIdx.x * 4096);
    int t = threadIdx.x, lane = t & 63, wv = t >> 6;
    u16x8v ca = row[t], cb = row[t + 256];
    float va[8], vb[8];
    float mx = -3.4e38f;
#pragma unroll
    for (int i = 0; i < 8; ++i) {
        va[i] = h2f(ca[i]); vb[i] = h2f(cb[i]);
        mx = fmaxf(mx, fmaxf(va[i], vb[i]));
    }
#pragma unroll
    for (int m = 1; m < 64; m <<= 1) mx = fmaxf(mx, __shfl_xor(mx, m));
    __shared__ float sM[4], sS[4];
    if (!lane) sM[wv] = mx;
    __syncthreads();
    mx = fmaxf(fmaxf(sM[0], sM[1]), fmaxf(sM[2], sM[3]));
    float sum = 0.f;
#pragma unroll
    for (int i = 0; i < 8; ++i) {
        va[i] = __expf(va[i] - mx);
        vb[i] = __expf(vb[i] - mx);
        sum += va[i] + vb[i];
    }
#pragma unroll
    for (int m = 1; m < 64; m <<= 1) sum += __shfl_xor(sum, m);
    if (!lane) sS[wv] = sum;
    __syncthreads();
    sum = sS[0] + sS[1] + sS[2] + sS[3];
    float inv = 1.0f / sum;
    u16x8v oa, ob;
#pragma unroll
    for (int i = 0; i < 8; ++i) {
        oa[i] = f2h(va[i] * inv);
        ob[i] = f2h(vb[i] * inv);
    }
    row[t] = oa; row[t + 256] = ob;
}

// -------------------------------------- split-K reduce + residual + v -----
__global__ void __launch_bounds__(256) reduce4resid(
    const u16* __restrict__ part, const float* __restrict__ xr,
    const float* __restrict__ v, float* __restrict__ out)
{
    const size_t PLANE = 2097152;
    int b = blockIdx.y;
    size_t g8 = ((size_t)blockIdx.x * 256 + threadIdx.x) * 8;
    const u16* p0 = part + (size_t)b * 4 * PLANE + g8;
    float acc[8] = {0.f, 0.f, 0.f, 0.f, 0.f, 0.f, 0.f, 0.f};
#pragma unroll
    for (int k = 0; k < 4; ++k) {
        u16x8v h = *(const u16x8v*)(p0 + (size_t)k * PLANE);
#pragma unroll
        for (int i = 0; i < 8; ++i) acc[i] += h2f(h[i]);
    }
    const float4* xv = (const float4*)(xr + (size_t)b * PLANE + g8);
    float4 x0 = xv[0], x1 = xv[1];
    float vc = v[g8 >> 12];
    float4 o0, o1;
    o0.x = acc[0] + x0.x + vc; o0.y = acc[1] + x0.y + vc;
    o0.z = acc[2] + x0.z + vc; o0.w = acc[3] + x0.w + vc;
    o1.x = acc[4] + x1.x + vc; o1.y = acc[5] + x1.y + vc;
    o1.z = acc[6] + x1.z + vc; o1.w = acc[7] + x1.w + vc;
    float4* op = (float4*)(out + (size_t)b * PLANE + g8);
    op[0] = o0; op[1] = o1;
}

// -------------------------------------------------------------- launch ----
extern "C" void kernel_launch(void* const* d_in, const int* in_sizes, int n_in,
                              void* d_out, int out_size, void* d_ws, size_t ws_size,
                              hipStream_t stream)
{
    const float* c   = (const float*)d_in[0];
    const float* s   = (const float*)d_in[1];
    const float* x   = (const float*)d_in[2];
    const float* c_w = (const float*)d_in[3];
    const float* c_b = (const float*)d_in[4];
    const float* s_w = (const float*)d_in[5];
    const float* s_b = (const float*)d_in[6];
    const float* i_w = (const float*)d_in[7];
    const float* i_b = (const float*)d_in[8];
    const float* o_w = (const float*)d_in[9];
    const float* o_b = (const float*)d_in[10];
    float* out = (float*)d_out;
    char* ws = (char*)d_ws;

    const int B = 4, C = 512, N = 4096;
    const size_t NC = (size_t)N * C;
    const size_t W2 = (size_t)C * C;
    const size_t NN = (size_t)N * N;
    const int SMEM256 = 65536;

    size_t off = 0;
    auto alloc = [&](size_t bytes) { size_t o = off; off += (bytes + 255) & ~(size_t)255; return o; };

    size_t o_meanC = alloc((size_t)B * C * 4);
    size_t o_rstdC = alloc((size_t)B * C * 4);
    size_t o_meanS = alloc((size_t)B * C * 4);
    size_t o_rstdS = alloc((size_t)B * C * 4);
    size_t o_cwT = alloc(W2 * 2);
    size_t o_swT = alloc(W2 * 2);
    size_t o_iwT = alloc(W2 * 2);
    size_t o_ow  = alloc(W2 * 2);
    size_t o_G   = alloc(W2 * 2);            // G[a,l] = c_w^T s_w
    size_t o_W   = alloc(W2 * 2);            // W = o_w @ i_w
    size_t o_Gb  = alloc((size_t)B * W2 * 2);// per-batch Gb = diag(rC)·G·diag(rS)
    size_t o_v   = alloc((size_t)C * 4);
    size_t o_wu  = alloc((size_t)C * 4);
    size_t o_wb  = alloc((size_t)B * C * 4); // per-batch rowdot vector
    size_t o_u   = alloc((size_t)B * N * 4);
    size_t o_pS  = alloc((size_t)8 * 512 * 128 * 4);  // stat partials
    size_t o_pQ  = alloc((size_t)8 * 512 * 128 * 4);
    size_t o_cT  = alloc(B * NC * 2);        // raw c transposed [B,N,C] f16
    size_t o_sT  = alloc(B * NC * 2);        // raw s transposed (PV + sg + rowdot)
    size_t o_sgT = alloc(B * NC * 2);        // sg[m,a] = Gb_b @ sT
    size_t o_sW  = alloc(B * NC * 2);        // sW[o,m] = W @ sT
    size_t o_P   = alloc(2 * NN * 2);        // PAIR logits/P f16 (67MB)
    size_t o_pt  = alloc(8 * NC * 2);        // pair split-K4 partials f16

    if (ws_size < off) {
        (void)hipMemsetAsync(d_out, 0, (size_t)out_size * 4, stream);
        return;
    }

    float* meanC = (float*)(ws + o_meanC);
    float* rstdC = (float*)(ws + o_rstdC);
    float* meanS = (float*)(ws + o_meanS);
    float* rstdS = (float*)(ws + o_rstdS);
    u16* cwT = (u16*)(ws + o_cwT);
    u16* swT = (u16*)(ws + o_swT);
    u16* iwT = (u16*)(ws + o_iwT);
    u16* ow  = (u16*)(ws + o_ow);
    u16* Gf  = (u16*)(ws + o_G);
    u16* Wf  = (u16*)(ws + o_W);
    u16* Gb  = (u16*)(ws + o_Gb);
    float* vb = (float*)(ws + o_v);
    float* wu = (float*)(ws + o_wu);
    float* wb = (float*)(ws + o_wb);
    float* ub = (float*)(ws + o_u);
    float* pS = (float*)(ws + o_pS);
    float* pQ = (float*)(ws + o_pQ);
    u16* cT  = (u16*)(ws + o_cT);
    u16* sT  = (u16*)(ws + o_sT);
    u16* sgT = (u16*)(ws + o_sgT);
    u16* sW  = (u16*)(ws + o_sW);
    u16* Pb  = (u16*)(ws + o_P);
    u16* partH = (u16*)(ws + o_pt);

    // 1) pack raw transposed f16 + stat partials (single fp32 pass)
    packstat<<<dim3(N / 32, C / 32, 8), dim3(32, 8), 0, stream>>>(
        c, s, cT, sT, pS, pQ);
    // 2) stats reduce -> mean/rstd per (tensor,batch,channel)
    statreduce<<<dim3(8 * 512), 64, 0, stream>>>(pS, pQ, meanC, rstdC, meanS, rstdS);
    // 3) weight preps
    prep_kernel<<<dim3(16, 16, 4), dim3(32, 8), 0, stream>>>(
        c_w, s_w, i_w, o_w, cwT, swT, iwT, ow);
    bias_prep<<<dim3(4), 256, 0, stream>>>(o_w, i_b, o_b, s_w, c_b, vb, wu);
    // G[a,l] = c_w^T s_w  and  W[o,c] = o_w i_w  in one dispatch
    gemm_bt<EPI_PLAIN_F16><<<dim3(4, 2, 2), 512, 0, stream>>>(
        cwT, swT, 512, 512, nullptr, nullptr, 0, nullptr, Gf, 512, 1,
        (long)(3 * W2), 0, (long)W2, 0, (long)W2);
    // 4) fold instance-norm into weights: Gb_b, wb_b (wave-parallel)
    wb_kernel<<<dim3(B * 512 / 4), 256, 0, stream>>>(Gf, wu, meanC, rstdC, rstdS, wb);
    gbscale<<<dim3(128, B), 256, 0, stream>>>(Gf, rstdC, rstdS, Gb);
    // 5) sgT[m,a] = sum_l sT[m,l]*Gb_b[a,l]  (natural [m,a])
    gemm_bt<EPI_PLAIN_F16><<<dim3(4, 16, B), 512, 0, stream>>>(
        sT, Gb, 512, 512, nullptr, nullptr, 0, nullptr, sgT, 512, 1,
        (long)NC, 0, (long)W2, 0, (long)NC);
    // 6) sW[o,m] = sum_c W[o,c]*sT[m,c]
    gemm_bt<EPI_PLAIN_F16><<<dim3(32, 2, B), 512, 0, stream>>>(
        Wf, sT, 512, 512, nullptr, nullptr, 0, nullptr, sW, 4096, 1,
        0, 0, (long)NC, 0, (long)NC);
    // 7) u[b,m] = sum_l sT[b,m,l]*wb[b,l]
    rowdot_kernel<<<dim3(B * N / 4), 256, 0, stream>>>(sT, wb, ub);
    // 8) attention in batch PAIRS — 256^2 2-phase logits, R12 engine PV
    for (int pb0 = 0; pb0 < B; pb0 += 2) {
        glogits256<<<dim3(16, 16, 2), 512, SMEM256, stream>>>(
            cT + (size_t)pb0 * NC, sgT + (size_t)pb0 * NC,
            ub + (size_t)pb0 * N, Pb,
            (long)NC, (long)NC, (long)N, (long)NN);
        softmax16<<<dim3(2 * N), 256, 0, stream>>>(Pb);
        gemm_bt<EPI_PLAIN_F16><<<dim3(32, 2, 8), 512, 0, stream>>>(
            sW + (size_t)pb0 * NC, Pb, 1024, 4096, nullptr, nullptr, 0,
            nullptr, partH, 4096, 4,
            (long)NC, 1024L, (long)NN, 1024L, (long)NC);
        reduce4resid<<<dim3((int)(NC / 2048), 2), 256, 0, stream>>>(
            partH, x + (size_t)pb0 * NC, vb, out + (size_t)pb0 * NC);
    }
}